// Round 3
// baseline (1979.646 us; speedup 1.0000x reference)
//
#include <hip/hip_runtime.h>
#include <hip/hip_bf16.h>

// Problem constants
#define B2    2
#define C     512
#define HH    128
#define WW    128
#define HW    16384
#define HEADS 64

typedef __attribute__((ext_vector_type(8))) short bf16x8;
typedef __attribute__((ext_vector_type(4))) float f32x4;

__device__ __forceinline__ float b2f(short s) {
    union { unsigned u; float f; } x;
    x.u = ((unsigned)(unsigned short)s) << 16;
    return x.f;
}
__device__ __forceinline__ short f2b(float f) {
    unsigned u; __builtin_memcpy(&u, &f, 4);
    unsigned r = u + 0x7FFFu + ((u >> 16) & 1u);   // RNE
    return (short)(r >> 16);
}

// ---------------------------------------------------------------------------
// K1: 1x1 conv as GEMM. Y[co][p] = sum_ci W[co_off+co][ci] * X[ci][p] (+bias).
// fp32 inputs converted to bf16 at LDS staging; bf16 MFMA 16x16x32, fp32 acc;
// bf16 output slab. Tile BM=128 x BN=128 x BK=32.
// ---------------------------------------------------------------------------
#define BM 128
#define BN 128
#define BK 32
#define LDK 40

struct GemmJob  { const float* X; const float* W; const float* bias; short* Y; int co_off; };
struct GemmJobs { GemmJob j[4]; };

__global__ __launch_bounds__(256) void k_gemm(GemmJobs jobs)
{
    __shared__ __align__(16) short As[BM * LDK];
    __shared__ __align__(16) short Bs[BN * LDK];

    const GemmJob jb = jobs.j[blockIdx.z];
    const float* X    = jb.X;
    const float* Wm   = jb.W;
    const float* bias = jb.bias;
    short*       Y    = jb.Y;
    const int co_off  = jb.co_off;

    const int co0 = blockIdx.x * BM;
    const int p0  = blockIdx.y * BN;

    const int t = threadIdx.x;
    const int lane = t & 63, wv = t >> 6;
    const int wm = (wv & 1) << 6, wn = (wv >> 1) << 6;   // wave tile origin
    const int l15 = lane & 15, quad = lane >> 4;
    const int rm = t & 127;              // staging row (m for A, n for B)
    const int kc = (t >> 7) << 4;        // staging k offset: 0 or 16

    f32x4 acc[4][4] = {};

    for (int kk = 0; kk < C; kk += BK) {
        // stage A: W[co_off+co0+rm][kk+kc .. +16) fp32 -> bf16
        const float* asrc = Wm + (size_t)(co_off + co0 + rm) * C + kk + kc;
        __align__(16) short abuf[16];
        #pragma unroll
        for (int j = 0; j < 4; ++j) {
            f32x4 v = *(const f32x4*)(asrc + j * 4);
            abuf[j * 4 + 0] = f2b(v[0]); abuf[j * 4 + 1] = f2b(v[1]);
            abuf[j * 4 + 2] = f2b(v[2]); abuf[j * 4 + 3] = f2b(v[3]);
        }
        // stage B (transpose): Bs[n][k] = X[kk+k][p0+n] fp32 -> bf16
        const float* bsrc = X + (size_t)(kk + kc) * HW + p0 + rm;
        __align__(16) short tmp[16];
        #pragma unroll
        for (int j = 0; j < 16; ++j) tmp[j] = f2b(bsrc[(size_t)j * HW]);

        *(bf16x8*)&As[rm * LDK + kc]     = *(const bf16x8*)abuf;
        *(bf16x8*)&As[rm * LDK + kc + 8] = *(const bf16x8*)(abuf + 8);
        *(bf16x8*)&Bs[rm * LDK + kc]     = *(const bf16x8*)tmp;
        *(bf16x8*)&Bs[rm * LDK + kc + 8] = *(const bf16x8*)(tmp + 8);
        __syncthreads();

        bf16x8 af[4], bfr[4];
        #pragma unroll
        for (int i = 0; i < 4; ++i)
            af[i]  = *(const bf16x8*)&As[(wm + i * 16 + l15) * LDK + quad * 8];
        #pragma unroll
        for (int i = 0; i < 4; ++i)
            bfr[i] = *(const bf16x8*)&Bs[(wn + i * 16 + l15) * LDK + quad * 8];
        #pragma unroll
        for (int i = 0; i < 4; ++i)
            #pragma unroll
            for (int j = 0; j < 4; ++j)
                acc[i][j] = __builtin_amdgcn_mfma_f32_16x16x32_bf16(af[i], bfr[j], acc[i][j], 0, 0, 0);
        __syncthreads();
    }

    // epilogue: C/D layout col = lane&15, row = quad*4 + reg (m89/m91-verified)
    #pragma unroll
    for (int i = 0; i < 4; ++i) {
        #pragma unroll
        for (int r = 0; r < 4; ++r) {
            const int co = co0 + wm + i * 16 + quad * 4 + r;
            const float bv = bias[co_off + co];
            #pragma unroll
            for (int j = 0; j < 4; ++j) {
                const int p = p0 + wn + j * 16 + l15;
                Y[(size_t)co * HW + p] = f2b(acc[i][j][r] + bv);
            }
        }
    }
}

// ---------------------------------------------------------------------------
// K2: stats for one (batch, type). dwconv q,k on the fly from bf16 slab,
// Gram S[8][8] + sumsq for l2 norms. q slab at qk, k slab at qk+512*HW.
// type 0: q=hsi-q, k=lidar-k -> dot1, sumsq kinds 0/1
// type 1: q=lidar-q, k=hsi-k -> dot2, sumsq kinds 2/3
// ---------------------------------------------------------------------------
__global__ __launch_bounds__(256) void k_stats(
    const short* __restrict__ qk,
    const float* __restrict__ dwh_w, const float* __restrict__ dwh_b,
    const float* __restrict__ dwl_w, const float* __restrict__ dwl_b,
    float* __restrict__ dot1, float* __restrict__ dot2, float* __restrict__ sumsq,
    int b, int type)
{
    __shared__ float wq[72], wk[72], bq[8], bk[8];
    const int chunk = blockIdx.x;     // 8 chunks of 2048 px
    const int h = blockIdx.y;
    const int qs = type;

    const float* qdw = qs ? dwl_w : dwh_w;
    const float* qdb = qs ? dwl_b : dwh_b;
    const float* kdw = qs ? dwh_w : dwl_w;
    const float* kdb = qs ? dwh_b : dwl_b;

    const int t = threadIdx.x;
    if (t < 72) { wq[t] = qdw[h * 72 + t]; wk[t] = kdw[C * 9 + h * 72 + t]; }
    if (t < 8)  { bq[t] = qdb[h * 8 + t];  bk[t] = kdb[C + h * 8 + t]; }
    __syncthreads();

    const short* qbase = qk + (size_t)(h * 8) * HW;
    const short* kbase = qk + (size_t)(C + h * 8) * HW;

    float S[8][8] = {};
    float qq[8] = {}, kq[8] = {};

    for (int it = 0; it < 8; ++it) {
        const int p = chunk * 2048 + it * 256 + t;
        const int row = p >> 7, col = p & 127;
        float qv[8], kv[8];
        #pragma unroll
        for (int d = 0; d < 8; ++d) {
            float aq = bq[d], ak = bk[d];
            const short* plq = qbase + (size_t)d * HW;
            const short* plk = kbase + (size_t)d * HW;
            #pragma unroll
            for (int dr = -1; dr <= 1; ++dr) {
                const int r2 = row + dr;
                if ((unsigned)r2 < (unsigned)HH) {
                    #pragma unroll
                    for (int dc = -1; dc <= 1; ++dc) {
                        const int c2 = col + dc;
                        if ((unsigned)c2 < (unsigned)WW) {
                            const int wi = d * 9 + (dr + 1) * 3 + dc + 1;
                            const int off = r2 * WW + c2;
                            aq += wq[wi] * b2f(plq[off]);
                            ak += wk[wi] * b2f(plk[off]);
                        }
                    }
                }
            }
            qv[d] = aq; kv[d] = ak;
        }
        #pragma unroll
        for (int i = 0; i < 8; ++i) {
            qq[i] += qv[i] * qv[i];
            kq[i] += kv[i] * kv[i];
            #pragma unroll
            for (int j = 0; j < 8; ++j) S[i][j] += qv[i] * kv[j];
        }
    }

    // wave butterfly reduce + one atomic per wave per value
    const int lane = t & 63;
    float* dotp = (type ? dot2 : dot1) + ((size_t)(b * HEADS + h) << 6);
    #pragma unroll
    for (int i = 0; i < 8; ++i) {
        #pragma unroll
        for (int j = 0; j < 8; ++j) {
            float v = S[i][j];
            v += __shfl_down(v, 32); v += __shfl_down(v, 16); v += __shfl_down(v, 8);
            v += __shfl_down(v, 4);  v += __shfl_down(v, 2);  v += __shfl_down(v, 1);
            if (lane == 0) atomicAdd(&dotp[i * 8 + j], v);
        }
        float v1 = qq[i];
        v1 += __shfl_down(v1, 32); v1 += __shfl_down(v1, 16); v1 += __shfl_down(v1, 8);
        v1 += __shfl_down(v1, 4);  v1 += __shfl_down(v1, 2);  v1 += __shfl_down(v1, 1);
        float v2 = kq[i];
        v2 += __shfl_down(v2, 32); v2 += __shfl_down(v2, 16); v2 += __shfl_down(v2, 8);
        v2 += __shfl_down(v2, 4);  v2 += __shfl_down(v2, 2);  v2 += __shfl_down(v2, 1);
        if (lane == 0) {
            atomicAdd(&sumsq[((type * 2) * 2 + b) * C + h * 8 + i], v1);
            atomicAdd(&sumsq[((type * 2 + 1) * 2 + b) * C + h * 8 + i], v2);
        }
    }
}

// ---------------------------------------------------------------------------
// K3: attn normalize + temp, proj conv1x1 + BN + ReLU, softmax -> a1, a2
// ---------------------------------------------------------------------------
__global__ __launch_bounds__(256) void k_fuse(
    const float* __restrict__ dot1, const float* __restrict__ dot2,
    const float* __restrict__ sumsq,
    const float* __restrict__ temp1, const float* __restrict__ temp2,
    const float* __restrict__ pw, const float* __restrict__ pb,
    const float* __restrict__ g, const float* __restrict__ be,
    const float* __restrict__ mu, const float* __restrict__ var,
    float* __restrict__ a1, float* __restrict__ a2)
{
    __shared__ float cat[128 * 64];
    __shared__ float fus[64 * 64];
    const int b = blockIdx.x;
    const int t = threadIdx.x;
    const float EPS = 1e-12f;

    for (int idx = t; idx < 128 * 64; idx += 256) {
        const int ic = idx >> 6, ij = idx & 63, i = ij >> 3, j = ij & 7;
        const int is2 = ic >> 6, h = ic & 63;
        const float* dp = is2 ? dot2 : dot1;
        const int qk = is2 * 2, kk = is2 * 2 + 1;
        const float nq = sqrtf(sumsq[(qk * 2 + b) * C + h * 8 + i]);
        const float nk = sqrtf(sumsq[(kk * 2 + b) * C + h * 8 + j]);
        const float tv = is2 ? temp2[h] : temp1[h];
        const float d = dp[((size_t)(b * HEADS + h) << 6) + ij];
        cat[idx] = d / (fmaxf(nq, EPS) * fmaxf(nk, EPS)) * tv;
    }
    __syncthreads();

    for (int idx = t; idx < 64 * 64; idx += 256) {
        const int hd = idx >> 6, ij = idx & 63;
        float acc = pb[hd];
        for (int ic = 0; ic < 128; ++ic)
            acc += pw[hd * 128 + ic] * cat[ic * 64 + ij];
        const float sc = g[hd] / sqrtf(var[hd] + 1e-5f);
        const float v = (acc - mu[hd]) * sc + be[hd];
        fus[idx] = fmaxf(v, 0.f);
    }
    __syncthreads();

    for (int r = t; r < 512; r += 256) {
        const int hd = r >> 3, i = r & 7;
        float v[8], mx, sum;
        mx = -1e30f;
        #pragma unroll
        for (int j = 0; j < 8; ++j) { v[j] = fus[(hd << 6) + i * 8 + j] + cat[(hd << 6) + i * 8 + j]; mx = fmaxf(mx, v[j]); }
        sum = 0.f;
        #pragma unroll
        for (int j = 0; j < 8; ++j) { v[j] = __expf(v[j] - mx); sum += v[j]; }
        #pragma unroll
        for (int j = 0; j < 8; ++j) a1[((size_t)(b * HEADS + hd) << 6) + i * 8 + j] = v[j] / sum;
        mx = -1e30f;
        #pragma unroll
        for (int j = 0; j < 8; ++j) { v[j] = fus[(hd << 6) + i * 8 + j] + cat[((64 + hd) << 6) + i * 8 + j]; mx = fmaxf(mx, v[j]); }
        sum = 0.f;
        #pragma unroll
        for (int j = 0; j < 8; ++j) { v[j] = __expf(v[j] - mx); sum += v[j]; }
        #pragma unroll
        for (int j = 0; j < 8; ++j) a2[((size_t)(b * HEADS + hd) << 6) + i * 8 + j] = v[j] / sum;
    }
}

// ---------------------------------------------------------------------------
// K4: output. dwconv(v) on the fly, out[i] = sum_d A[i][d]*v[d] + v[i] + x[i]
// v slab layout: v + (zb*512 + ch)*HW (zb = s*2+b). x fp32, out fp32.
// ---------------------------------------------------------------------------
__global__ __launch_bounds__(256) void k_out(
    const short* __restrict__ v,
    const float* __restrict__ hsi, const float* __restrict__ lidar,
    const float* __restrict__ dwh_w, const float* __restrict__ dwh_b,
    const float* __restrict__ dwl_w, const float* __restrict__ dwl_b,
    const float* __restrict__ a1, const float* __restrict__ a2,
    float* __restrict__ out)
{
    __shared__ float A[64];
    __shared__ float wv[72], bv[8];
    const int chunk = blockIdx.x, h = blockIdx.y, zb = blockIdx.z;
    const int s = zb >> 1, b = zb & 1;
    const int t = threadIdx.x;

    const float* x   = (s ? lidar : hsi) + (size_t)b * C * HW;
    const float* dww = s ? dwl_w : dwh_w;
    const float* dwb = s ? dwl_b : dwh_b;
    const float* Ag  = (s ? a2 : a1) + ((size_t)(b * HEADS + h) << 6);
    if (t < 64) A[t] = Ag[t];
    if (t < 72) wv[t] = dww[(2 * C + h * 8) * 9 + t];
    if (t < 8)  bv[t] = dwb[2 * C + h * 8 + t];
    __syncthreads();

    const short* ybase = v + ((size_t)(zb * 512 + h * 8)) * HW;
    const float* xbase = x + (size_t)(h * 8) * HW;
    float* obase = out + ((size_t)((s * B2 + b) * C + h * 8)) * HW;

    for (int it = 0; it < 8; ++it) {
        const int p = chunk * 2048 + it * 256 + t;
        const int row = p >> 7, col = p & 127;
        float vvv[8];
        #pragma unroll
        for (int d = 0; d < 8; ++d) {
            float a = bv[d];
            const short* pl = ybase + (size_t)d * HW;
            #pragma unroll
            for (int dr = -1; dr <= 1; ++dr) {
                const int r2 = row + dr;
                if ((unsigned)r2 < (unsigned)HH) {
                    #pragma unroll
                    for (int dc = -1; dc <= 1; ++dc) {
                        const int c2 = col + dc;
                        if ((unsigned)c2 < (unsigned)WW)
                            a += wv[d * 9 + (dr + 1) * 3 + dc + 1] * b2f(pl[r2 * WW + c2]);
                    }
                }
            }
            vvv[d] = a;
        }
        #pragma unroll
        for (int i = 0; i < 8; ++i) {
            float o = vvv[i];
            #pragma unroll
            for (int d = 0; d < 8; ++d) o += A[i * 8 + d] * vvv[d];
            o += xbase[(size_t)i * HW + p];
            obase[(size_t)i * HW + p] = o;
        }
    }
}

// ---------------------------------------------------------------------------
extern "C" void kernel_launch(void* const* d_in, const int* in_sizes, int n_in,
                              void* d_out, int out_size, void* d_ws, size_t ws_size,
                              hipStream_t stream)
{
    const float* hsi  = (const float*)d_in[0];
    const float* lidar= (const float*)d_in[1];
    const float* hqw  = (const float*)d_in[2];
    const float* hqb  = (const float*)d_in[3];
    const float* lqw  = (const float*)d_in[4];
    const float* lqb  = (const float*)d_in[5];
    const float* hdw  = (const float*)d_in[6];
    const float* hdb  = (const float*)d_in[7];
    const float* ldw  = (const float*)d_in[8];
    const float* ldb  = (const float*)d_in[9];
    const float* t1   = (const float*)d_in[10];
    const float* t2   = (const float*)d_in[11];
    const float* pw   = (const float*)d_in[12];
    const float* pb   = (const float*)d_in[13];
    const float* bg   = (const float*)d_in[14];
    const float* bb   = (const float*)d_in[15];
    const float* bm   = (const float*)d_in[16];
    const float* bvv  = (const float*)d_in[17];

    // Workspace layout:
    //   [0, 147456)        fp32 stats: dot1, dot2, sumsq, a1, a2
    //   [147456, +32 MiB)  bf16 slab: per-phase q/k (1024 ch) or v (4x512 ch)
    // Peak need: 147456 + 33554432 = 33.7 MB.
    char* ws = (char*)d_ws;
    float* dot1  = (float*)ws;                               // [2][64][8][8]
    float* dot2  = dot1 + 2 * HEADS * 64;
    float* sumsq = dot2 + 2 * HEADS * 64;                    // [4][2][512]
    float* a1    = sumsq + 4 * 2 * C;
    float* a2    = a1 + 2 * HEADS * 64;
    short* slab  = (short*)(ws + 147456);                    // 32 MiB

    const size_t statbytes = (size_t)(2 * HEADS * 64 * 2 + 4 * 2 * C) * sizeof(float);
    hipMemsetAsync(dot1, 0, statbytes, stream);

    // Phase 1: per (batch, type): GEMM q-stream q + k-stream k, then stats.
    for (int b = 0; b < 2; ++b) {
        for (int type = 0; type < 2; ++type) {
            const float* qx = (type ? lidar : hsi) + (size_t)b * C * HW;
            const float* kx = (type ? hsi : lidar) + (size_t)b * C * HW;
            const float* qw = type ? lqw : hqw;  const float* qb = type ? lqb : hqb;
            const float* kw = type ? hqw : lqw;  const float* kb = type ? hqb : lqb;
            GemmJobs jj;
            jj.j[0] = { qx, qw, qb, slab,                     0 };   // q: W rows [0,512)
            jj.j[1] = { kx, kw, kb, slab + (size_t)C * HW,  C };     // k: W rows [512,1024)
            jj.j[2] = jj.j[0]; jj.j[3] = jj.j[0];
            k_gemm<<<dim3(4, 128, 2), 256, 0, stream>>>(jj);
            k_stats<<<dim3(8, 64, 1), 256, 0, stream>>>(
                slab, hdw, hdb, ldw, ldb, dot1, dot2, sumsq, b, type);
        }
    }

    // Phase 2: GEMM v for all 4 (s,b) into slab (reused).
    GemmJobs vj;
    vj.j[0] = { hsi,                      hqw, hqb, slab,                          2 * C };
    vj.j[1] = { hsi   + (size_t)C * HW,   hqw, hqb, slab + (size_t)C * HW,     2 * C };
    vj.j[2] = { lidar,                    lqw, lqb, slab + (size_t)2 * C * HW, 2 * C };
    vj.j[3] = { lidar + (size_t)C * HW,   lqw, lqb, slab + (size_t)3 * C * HW, 2 * C };
    k_gemm<<<dim3(4, 128, 4), 256, 0, stream>>>(vj);

    // Phase 3: fuse scores -> a1,a2 ; Phase 4: outputs.
    k_fuse<<<dim3(2, 1, 1), 256, 0, stream>>>(dot1, dot2, sumsq, t1, t2,
                                              pw, pb, bg, bb, bm, bvv, a1, a2);
    k_out<<<dim3(8, 64, 4), 256, 0, stream>>>(slab, hsi, lidar,
                                              hdw, hdb, ldw, ldb, a1, a2,
                                              (float*)d_out);
}

// Round 4
// 1111.945 us; speedup vs baseline: 1.7803x; 1.7803x over previous
//
#include <hip/hip_runtime.h>
#include <hip/hip_bf16.h>

// Problem constants
#define B2    2
#define C     512
#define HH    128
#define WW    128
#define HW    16384
#define HEADS 64

typedef __attribute__((ext_vector_type(8))) short bf16x8;
typedef __attribute__((ext_vector_type(4))) float f32x4;

__device__ __forceinline__ float b2f(short s) {
    union { unsigned u; float f; } x;
    x.u = ((unsigned)(unsigned short)s) << 16;
    return x.f;
}
__device__ __forceinline__ short f2b(float f) {
    unsigned u; __builtin_memcpy(&u, &f, 4);
    unsigned r = u + 0x7FFFu + ((u >> 16) & 1u);   // RNE
    return (short)(r >> 16);
}

// ---------------------------------------------------------------------------
// Vectorized 3x3 depthwise conv for one channel, 8 consecutive pixels/thread.
// Thread layout: 16 lanes span one 128-px row (col0 = (lane&15)*8). Column
// halo via __shfl from lane+-1 (vector end elements); row halo via zeroed
// payload (uniform shuffles). 'SAME' zero padding at image borders.
// ---------------------------------------------------------------------------
__device__ __forceinline__ void conv8(
    const short* __restrict__ plane, int row, int lane, int cg,
    const float* __restrict__ w9, float bias0, float* o)
{
    #pragma unroll
    for (int i = 0; i < 8; ++i) o[i] = bias0;
    #pragma unroll
    for (int dr = 0; dr < 3; ++dr) {
        const int r2 = row + dr - 1;
        const bool ok = (unsigned)r2 < (unsigned)HH;
        bf16x8 v = {0, 0, 0, 0, 0, 0, 0, 0};
        if (ok) v = *(const bf16x8*)(plane + (size_t)r2 * WW);
        float rv[10];
        #pragma unroll
        for (int j = 0; j < 8; ++j) rv[1 + j] = b2f(v[j]);
        const float lf = __shfl(rv[8], lane - 1);   // neighbor's col0+7 = my col0-1
        const float rt = __shfl(rv[1], lane + 1);   // neighbor's col0   = my col0+8
        rv[0] = (cg == 0)  ? 0.f : lf;
        rv[9] = (cg == 15) ? 0.f : rt;
        const float w0 = w9[dr * 3], w1 = w9[dr * 3 + 1], w2 = w9[dr * 3 + 2];
        #pragma unroll
        for (int i = 0; i < 8; ++i)
            o[i] += w0 * rv[i] + w1 * rv[i + 1] + w2 * rv[i + 2];
    }
}

// ---------------------------------------------------------------------------
// K1: 1x1 conv as GEMM (unchanged from R3). fp32 -> bf16 at staging, MFMA
// 16x16x32, bf16 output slab.
// ---------------------------------------------------------------------------
#define BM 128
#define BN 128
#define BK 32
#define LDK 40

struct GemmJob  { const float* X; const float* W; const float* bias; short* Y; int co_off; };
struct GemmJobs { GemmJob j[4]; };

__global__ __launch_bounds__(256) void k_gemm(GemmJobs jobs)
{
    __shared__ __align__(16) short As[BM * LDK];
    __shared__ __align__(16) short Bs[BN * LDK];

    const GemmJob jb = jobs.j[blockIdx.z];
    const float* X    = jb.X;
    const float* Wm   = jb.W;
    const float* bias = jb.bias;
    short*       Y    = jb.Y;
    const int co_off  = jb.co_off;

    const int co0 = blockIdx.x * BM;
    const int p0  = blockIdx.y * BN;

    const int t = threadIdx.x;
    const int lane = t & 63, wv = t >> 6;
    const int wm = (wv & 1) << 6, wn = (wv >> 1) << 6;
    const int l15 = lane & 15, quad = lane >> 4;
    const int rm = t & 127;
    const int kc = (t >> 7) << 4;

    f32x4 acc[4][4] = {};

    for (int kk = 0; kk < C; kk += BK) {
        const float* asrc = Wm + (size_t)(co_off + co0 + rm) * C + kk + kc;
        __align__(16) short abuf[16];
        #pragma unroll
        for (int j = 0; j < 4; ++j) {
            f32x4 v = *(const f32x4*)(asrc + j * 4);
            abuf[j * 4 + 0] = f2b(v[0]); abuf[j * 4 + 1] = f2b(v[1]);
            abuf[j * 4 + 2] = f2b(v[2]); abuf[j * 4 + 3] = f2b(v[3]);
        }
        const float* bsrc = X + (size_t)(kk + kc) * HW + p0 + rm;
        __align__(16) short tmp[16];
        #pragma unroll
        for (int j = 0; j < 16; ++j) tmp[j] = f2b(bsrc[(size_t)j * HW]);

        *(bf16x8*)&As[rm * LDK + kc]     = *(const bf16x8*)abuf;
        *(bf16x8*)&As[rm * LDK + kc + 8] = *(const bf16x8*)(abuf + 8);
        *(bf16x8*)&Bs[rm * LDK + kc]     = *(const bf16x8*)tmp;
        *(bf16x8*)&Bs[rm * LDK + kc + 8] = *(const bf16x8*)(tmp + 8);
        __syncthreads();

        bf16x8 af[4], bfr[4];
        #pragma unroll
        for (int i = 0; i < 4; ++i)
            af[i]  = *(const bf16x8*)&As[(wm + i * 16 + l15) * LDK + quad * 8];
        #pragma unroll
        for (int i = 0; i < 4; ++i)
            bfr[i] = *(const bf16x8*)&Bs[(wn + i * 16 + l15) * LDK + quad * 8];
        #pragma unroll
        for (int i = 0; i < 4; ++i)
            #pragma unroll
            for (int j = 0; j < 4; ++j)
                acc[i][j] = __builtin_amdgcn_mfma_f32_16x16x32_bf16(af[i], bfr[j], acc[i][j], 0, 0, 0);
        __syncthreads();
    }

    #pragma unroll
    for (int i = 0; i < 4; ++i) {
        #pragma unroll
        for (int r = 0; r < 4; ++r) {
            const int co = co0 + wm + i * 16 + quad * 4 + r;
            const float bv = bias[co_off + co];
            #pragma unroll
            for (int j = 0; j < 4; ++j) {
                const int p = p0 + wn + j * 16 + l15;
                Y[(size_t)co * HW + p] = f2b(acc[i][j][r] + bv);
            }
        }
    }
}

// ---------------------------------------------------------------------------
// K2: stats for one (batch, type), vectorized. Each thread: one 8-px group,
// all 8 q-channels (packed bf16) then 8 k-channels, S[8][8]+norms in regs,
// butterfly reduce, atomics.
// ---------------------------------------------------------------------------
__global__ __launch_bounds__(256) void k_stats(
    const short* __restrict__ qk,
    const float* __restrict__ dwh_w, const float* __restrict__ dwh_b,
    const float* __restrict__ dwl_w, const float* __restrict__ dwl_b,
    float* __restrict__ dot1, float* __restrict__ dot2, float* __restrict__ sumsq,
    int b, int type)
{
    __shared__ float wq[72], wk[72], bq[8], bk[8];
    const int chunk = blockIdx.x;     // 8 chunks of 16 rows
    const int h = blockIdx.y;

    const float* qdw = type ? dwl_w : dwh_w;
    const float* qdb = type ? dwl_b : dwh_b;
    const float* kdw = type ? dwh_w : dwl_w;
    const float* kdb = type ? dwh_b : dwl_b;

    const int t = threadIdx.x;
    if (t < 72) { wq[t] = qdw[h * 72 + t]; wk[t] = kdw[C * 9 + h * 72 + t]; }
    if (t < 8)  { bq[t] = qdb[h * 8 + t];  bk[t] = kdb[C + h * 8 + t]; }
    __syncthreads();

    const int lane = t & 63, cg = t & 15;
    const int row = chunk * 16 + (t >> 4);
    const int col0 = cg << 3;

    const short* qbase = qk + (size_t)(h * 8) * HW + col0;
    const short* kbase = qk + (size_t)(C + h * 8) * HW + col0;

    // Phase A: q channels -> packed bf16 + qq
    bf16x8 vq[8];
    float qq[8];
    #pragma unroll
    for (int d = 0; d < 8; ++d) {
        float o[8];
        conv8(qbase + (size_t)d * HW, row, lane, cg, wq + d * 9, bq[d], o);
        float s2 = 0.f;
        bf16x8 pk;
        #pragma unroll
        for (int px = 0; px < 8; ++px) { s2 += o[px] * o[px]; pk[px] = f2b(o[px]); }
        qq[d] = s2;
        vq[d] = pk;
    }

    // Phase B: k channels -> S, kq
    float S[8][8];
    float kq[8];
    #pragma unroll
    for (int j = 0; j < 8; ++j) {
        float o[8];
        conv8(kbase + (size_t)j * HW, row, lane, cg, wk + j * 9, bk[j], o);
        float s2 = 0.f;
        #pragma unroll
        for (int px = 0; px < 8; ++px) s2 += o[px] * o[px];
        kq[j] = s2;
        #pragma unroll
        for (int i = 0; i < 8; ++i) {
            float a = 0.f;
            #pragma unroll
            for (int px = 0; px < 8; ++px) a += b2f(vq[i][px]) * o[px];
            S[i][j] = a;
        }
    }

    // wave butterfly reduce + one atomic per wave per value
    float* dotp = (type ? dot2 : dot1) + ((size_t)(b * HEADS + h) << 6);
    #pragma unroll
    for (int i = 0; i < 8; ++i) {
        #pragma unroll
        for (int j = 0; j < 8; ++j) {
            float v = S[i][j];
            v += __shfl_down(v, 32); v += __shfl_down(v, 16); v += __shfl_down(v, 8);
            v += __shfl_down(v, 4);  v += __shfl_down(v, 2);  v += __shfl_down(v, 1);
            if (lane == 0) atomicAdd(&dotp[i * 8 + j], v);
        }
        float v1 = qq[i];
        v1 += __shfl_down(v1, 32); v1 += __shfl_down(v1, 16); v1 += __shfl_down(v1, 8);
        v1 += __shfl_down(v1, 4);  v1 += __shfl_down(v1, 2);  v1 += __shfl_down(v1, 1);
        float v2 = kq[i];
        v2 += __shfl_down(v2, 32); v2 += __shfl_down(v2, 16); v2 += __shfl_down(v2, 8);
        v2 += __shfl_down(v2, 4);  v2 += __shfl_down(v2, 2);  v2 += __shfl_down(v2, 1);
        if (lane == 0) {
            atomicAdd(&sumsq[((type * 2) * 2 + b) * C + h * 8 + i], v1);
            atomicAdd(&sumsq[((type * 2 + 1) * 2 + b) * C + h * 8 + i], v2);
        }
    }
}

// ---------------------------------------------------------------------------
// K3: attn normalize + temp, proj conv1x1 + BN + ReLU, softmax -> a1, a2
// (unchanged from R3)
// ---------------------------------------------------------------------------
__global__ __launch_bounds__(256) void k_fuse(
    const float* __restrict__ dot1, const float* __restrict__ dot2,
    const float* __restrict__ sumsq,
    const float* __restrict__ temp1, const float* __restrict__ temp2,
    const float* __restrict__ pw, const float* __restrict__ pb,
    const float* __restrict__ g, const float* __restrict__ be,
    const float* __restrict__ mu, const float* __restrict__ var,
    float* __restrict__ a1, float* __restrict__ a2)
{
    __shared__ float cat[128 * 64];
    __shared__ float fus[64 * 64];
    const int b = blockIdx.x;
    const int t = threadIdx.x;
    const float EPS = 1e-12f;

    for (int idx = t; idx < 128 * 64; idx += 256) {
        const int ic = idx >> 6, ij = idx & 63, i = ij >> 3, j = ij & 7;
        const int is2 = ic >> 6, h = ic & 63;
        const float* dp = is2 ? dot2 : dot1;
        const int qkk = is2 * 2, kkk = is2 * 2 + 1;
        const float nq = sqrtf(sumsq[(qkk * 2 + b) * C + h * 8 + i]);
        const float nk = sqrtf(sumsq[(kkk * 2 + b) * C + h * 8 + j]);
        const float tv = is2 ? temp2[h] : temp1[h];
        const float d = dp[((size_t)(b * HEADS + h) << 6) + ij];
        cat[idx] = d / (fmaxf(nq, EPS) * fmaxf(nk, EPS)) * tv;
    }
    __syncthreads();

    for (int idx = t; idx < 64 * 64; idx += 256) {
        const int hd = idx >> 6, ij = idx & 63;
        float acc = pb[hd];
        for (int ic = 0; ic < 128; ++ic)
            acc += pw[hd * 128 + ic] * cat[ic * 64 + ij];
        const float sc = g[hd] / sqrtf(var[hd] + 1e-5f);
        const float v = (acc - mu[hd]) * sc + be[hd];
        fus[idx] = fmaxf(v, 0.f);
    }
    __syncthreads();

    for (int r = t; r < 512; r += 256) {
        const int hd = r >> 3, i = r & 7;
        float v[8], mx, sum;
        mx = -1e30f;
        #pragma unroll
        for (int j = 0; j < 8; ++j) { v[j] = fus[(hd << 6) + i * 8 + j] + cat[(hd << 6) + i * 8 + j]; mx = fmaxf(mx, v[j]); }
        sum = 0.f;
        #pragma unroll
        for (int j = 0; j < 8; ++j) { v[j] = __expf(v[j] - mx); sum += v[j]; }
        #pragma unroll
        for (int j = 0; j < 8; ++j) a1[((size_t)(b * HEADS + hd) << 6) + i * 8 + j] = v[j] / sum;
        mx = -1e30f;
        #pragma unroll
        for (int j = 0; j < 8; ++j) { v[j] = fus[(hd << 6) + i * 8 + j] + cat[((64 + hd) << 6) + i * 8 + j]; mx = fmaxf(mx, v[j]); }
        sum = 0.f;
        #pragma unroll
        for (int j = 0; j < 8; ++j) { v[j] = __expf(v[j] - mx); sum += v[j]; }
        #pragma unroll
        for (int j = 0; j < 8; ++j) a2[((size_t)(b * HEADS + hd) << 6) + i * 8 + j] = v[j] / sum;
    }
}

// ---------------------------------------------------------------------------
// K4: output, vectorized. dwconv(v) per thread (8 px x 8 ch in regs),
// out[i] = x[i] + v[i] + sum_d A[i][d]*v[d], f32x4 loads/stores.
// ---------------------------------------------------------------------------
__global__ __launch_bounds__(256) void k_out(
    const short* __restrict__ v,
    const float* __restrict__ hsi, const float* __restrict__ lidar,
    const float* __restrict__ dwh_w, const float* __restrict__ dwh_b,
    const float* __restrict__ dwl_w, const float* __restrict__ dwl_b,
    const float* __restrict__ a1, const float* __restrict__ a2,
    float* __restrict__ out)
{
    __shared__ float A[64];
    __shared__ float wv[72], bvs[8];
    const int chunk = blockIdx.x, h = blockIdx.y, zb = blockIdx.z;
    const int s = zb >> 1, b = zb & 1;
    const int t = threadIdx.x;

    const float* x   = (s ? lidar : hsi) + (size_t)b * C * HW;
    const float* dww = s ? dwl_w : dwh_w;
    const float* dwb = s ? dwl_b : dwh_b;
    const float* Ag  = (s ? a2 : a1) + ((size_t)(b * HEADS + h) << 6);
    if (t < 64) A[t] = Ag[t];
    if (t < 72) wv[t] = dww[(2 * C + h * 8) * 9 + t];
    if (t < 8)  bvs[t] = dwb[2 * C + h * 8 + t];
    __syncthreads();

    const int lane = t & 63, cg = t & 15;
    const int row = chunk * 16 + (t >> 4);
    const int col0 = cg << 3;

    const short* ybase = v + ((size_t)(zb * 512 + h * 8)) * HW + col0;
    const float* xbase = x + (size_t)(h * 8) * HW + (size_t)row * WW + col0;
    float* obase = out + ((size_t)((s * B2 + b) * C + h * 8)) * HW + (size_t)row * WW + col0;

    float vv[8][8];
    #pragma unroll
    for (int d = 0; d < 8; ++d)
        conv8(ybase + (size_t)d * HW, row, lane, cg, wv + d * 9, bvs[d], vv[d]);

    #pragma unroll
    for (int i = 0; i < 8; ++i) {
        f32x4 x0 = *(const f32x4*)(xbase + (size_t)i * HW);
        f32x4 x1 = *(const f32x4*)(xbase + (size_t)i * HW + 4);
        float o[8];
        #pragma unroll
        for (int px = 0; px < 8; ++px)
            o[px] = vv[i][px] + (px < 4 ? x0[px & 3] : x1[px & 3]);
        #pragma unroll
        for (int d = 0; d < 8; ++d) {
            const float ad = A[i * 8 + d];
            #pragma unroll
            for (int px = 0; px < 8; ++px) o[px] += ad * vv[d][px];
        }
        f32x4 o0 = { o[0], o[1], o[2], o[3] };
        f32x4 o1 = { o[4], o[5], o[6], o[7] };
        *(f32x4*)(obase + (size_t)i * HW)     = o0;
        *(f32x4*)(obase + (size_t)i * HW + 4) = o1;
    }
}

// ---------------------------------------------------------------------------
extern "C" void kernel_launch(void* const* d_in, const int* in_sizes, int n_in,
                              void* d_out, int out_size, void* d_ws, size_t ws_size,
                              hipStream_t stream)
{
    const float* hsi  = (const float*)d_in[0];
    const float* lidar= (const float*)d_in[1];
    const float* hqw  = (const float*)d_in[2];
    const float* hqb  = (const float*)d_in[3];
    const float* lqw  = (const float*)d_in[4];
    const float* lqb  = (const float*)d_in[5];
    const float* hdw  = (const float*)d_in[6];
    const float* hdb  = (const float*)d_in[7];
    const float* ldw  = (const float*)d_in[8];
    const float* ldb  = (const float*)d_in[9];
    const float* t1   = (const float*)d_in[10];
    const float* t2   = (const float*)d_in[11];
    const float* pw   = (const float*)d_in[12];
    const float* pb   = (const float*)d_in[13];
    const float* bg   = (const float*)d_in[14];
    const float* bb   = (const float*)d_in[15];
    const float* bm   = (const float*)d_in[16];
    const float* bvv  = (const float*)d_in[17];

    // Workspace: [0,147456) fp32 stats; [147456, +32 MiB) bf16 slab. ~33.7 MB.
    char* ws = (char*)d_ws;
    float* dot1  = (float*)ws;                               // [2][64][8][8]
    float* dot2  = dot1 + 2 * HEADS * 64;
    float* sumsq = dot2 + 2 * HEADS * 64;                    // [4][2][512]
    float* a1    = sumsq + 4 * 2 * C;
    float* a2    = a1 + 2 * HEADS * 64;
    short* slab  = (short*)(ws + 147456);                    // 32 MiB

    const size_t statbytes = (size_t)(2 * HEADS * 64 * 2 + 4 * 2 * C) * sizeof(float);
    hipMemsetAsync(dot1, 0, statbytes, stream);

    // Phase 1: per (batch, type): GEMM q-stream q + k-stream k, then stats.
    for (int b = 0; b < 2; ++b) {
        for (int type = 0; type < 2; ++type) {
            const float* qx = (type ? lidar : hsi) + (size_t)b * C * HW;
            const float* kx = (type ? hsi : lidar) + (size_t)b * C * HW;
            const float* qw = type ? lqw : hqw;  const float* qb = type ? lqb : hqb;
            const float* kw = type ? hqw : lqw;  const float* kb = type ? hqb : lqb;
            GemmJobs jj;
            jj.j[0] = { qx, qw, qb, slab,                    0 };   // q: W rows [0,512)
            jj.j[1] = { kx, kw, kb, slab + (size_t)C * HW,   C };   // k: W rows [512,1024)
            jj.j[2] = jj.j[0]; jj.j[3] = jj.j[0];
            k_gemm<<<dim3(4, 128, 2), 256, 0, stream>>>(jj);
            k_stats<<<dim3(8, 64, 1), 256, 0, stream>>>(
                slab, hdw, hdb, ldw, ldb, dot1, dot2, sumsq, b, type);
        }
    }

    // Phase 2: GEMM v for all 4 (s,b) into slab (reused).
    GemmJobs vj;
    vj.j[0] = { hsi,                      hqw, hqb, slab,                        2 * C };
    vj.j[1] = { hsi   + (size_t)C * HW,   hqw, hqb, slab + (size_t)C * HW,       2 * C };
    vj.j[2] = { lidar,                    lqw, lqb, slab + (size_t)2 * C * HW,   2 * C };
    vj.j[3] = { lidar + (size_t)C * HW,   lqw, lqb, slab + (size_t)3 * C * HW,   2 * C };
    k_gemm<<<dim3(4, 128, 4), 256, 0, stream>>>(vj);

    // Phase 3: fuse scores -> a1,a2 ; Phase 4: outputs.
    k_fuse<<<dim3(2, 1, 1), 256, 0, stream>>>(dot1, dot2, sumsq, t1, t2,
                                              pw, pb, bg, bb, bm, bvv, a1, a2);
    k_out<<<dim3(8, 64, 4), 256, 0, stream>>>(slab, hsi, lidar,
                                              hdw, hdb, ldw, ldb, a1, a2,
                                              (float*)d_out);
}